// Round 3
// baseline (10541.052 us; speedup 1.0000x reference)
//
#include <hip/hip_runtime.h>
#include <float.h>

#define KDEP 72
#define CSZ  1024
#define DDIM 128
#define MT   64          // tokens per block
#define TILE_CW 64       // codewords per LDS tile
#define NTILES 16
#define NTHREADS 256
#define NBLK 512         // 32768 / MT

// Pure-f32 chain, bit-exact-order variant "A":
//   dot(r,e)   = sequential FMA over d = 0..127 ascending  (BLAS/Eigen k-loop order)
//   ||e||^2    = numpy pairwise-8: lanes r_j = sum_i p[8i+j] (plain adds on rounded
//                p=fl(e*e)), tree ((r0+r1)+(r2+r3))+((r4+r5)+(r6+r7))
//   dist       = fl(ee - 2*dot)   (2*dot exact)
//   update     = r = fl(r - e[idx]) elementwise, f32 state
//   argmin     = first occurrence (strict <, ties -> lowest index)
__launch_bounds__(NTHREADS, 2)
__global__ void rvq_encode_f32(const float* __restrict__ embs,
                               const float* __restrict__ r_in,
                               int* __restrict__ code_out)
{
    __shared__ float4 r32[MT * 33];        // [tok][33 float4] padded rows (132 floats)
    __shared__ float4 e32[TILE_CW * 33];   // [cw][33 float4]
    __shared__ float  eet[TILE_CW];
    __shared__ float  mrg_m[MT][17];
    __shared__ int    mrg_i[MT][17];
    __shared__ int    idxd[MT];

    const int tid  = threadIdx.x;
    const int tg   = tid >> 4;
    const int cg   = tid & 15;
    const int tok0 = tg * 4;
    const long gtok0 = (long)blockIdx.x * MT;

    // ---- init f32 residual state in LDS ----
    {
        const int tok = tid >> 2, q = tid & 3;     // 4 threads/token, 32 floats each
        const float4* rsrc = (const float4*)(r_in + (size_t)(gtok0 + tok) * DDIM) + q * 8;
        #pragma unroll
        for (int t = 0; t < 8; ++t) r32[tok * 33 + q * 8 + t] = rsrc[t];
    }

    for (int k = 0; k < KDEP; ++k) {
        const float* ek = embs + (size_t)k * (CSZ * DDIM);
        float m1[4];
        int   i1[4];
        #pragma unroll
        for (int i = 0; i < 4; ++i) { m1[i] = FLT_MAX; i1[i] = 0; }

        for (int tile = 0; tile < NTILES; ++tile) {
            const int c0 = tile * TILE_CW;
            __syncthreads();   // prior readers of e32/eet done; prev-depth r32 writes done

            // ---- stage codebook tile (coalesced float4) ----
            {
                const float4* gsrc = (const float4*)(ek + (size_t)c0 * DDIM);
                #pragma unroll
                for (int it = 0; it < 8; ++it) {
                    int u  = it * NTHREADS + tid;     // 0..2047 float4 chunks
                    int cw = u >> 5, c4 = u & 31;
                    e32[cw * 33 + c4] = gsrc[(size_t)cw * 32 + c4];
                }
            }
            __syncthreads();

            // ---- ||e||^2: numpy pairwise-8 emulation, 1 thread/codeword ----
            if (tid < TILE_CW) {
                float r8[8];
                #pragma unroll
                for (int j = 0; j < 8; ++j) r8[j] = 0.0f;
                for (int i = 0; i < 16; ++i) {        // dims 8i..8i+7
                    float4 va = e32[tid * 33 + 2 * i];
                    float4 vb = e32[tid * 33 + 2 * i + 1];
                    float p0 = va.x * va.x; asm volatile("" : "+v"(p0));
                    float p1 = va.y * va.y; asm volatile("" : "+v"(p1));
                    float p2 = va.z * va.z; asm volatile("" : "+v"(p2));
                    float p3 = va.w * va.w; asm volatile("" : "+v"(p3));
                    float p4 = vb.x * vb.x; asm volatile("" : "+v"(p4));
                    float p5 = vb.y * vb.y; asm volatile("" : "+v"(p5));
                    float p6 = vb.z * vb.z; asm volatile("" : "+v"(p6));
                    float p7 = vb.w * vb.w; asm volatile("" : "+v"(p7));
                    r8[0] += p0; r8[1] += p1; r8[2] += p2; r8[3] += p3;
                    r8[4] += p4; r8[5] += p5; r8[6] += p6; r8[7] += p7;
                }
                eet[tid] = ((r8[0] + r8[1]) + (r8[2] + r8[3]))
                         + ((r8[4] + r8[5]) + (r8[6] + r8[7]));
            }
            __syncthreads();

            // ---- bulk f32 dots: 4 tokens x 4 codewords, sequential-FMA over d ----
            float acc[4][4];
            #pragma unroll
            for (int i = 0; i < 4; ++i)
                #pragma unroll
                for (int j = 0; j < 4; ++j) acc[i][j] = 0.0f;

            for (int d4 = 0; d4 < 32; ++d4) {         // ascending d, 4 dims/step
                float4 rv[4], ev[4];
                #pragma unroll
                for (int i = 0; i < 4; ++i) rv[i] = r32[(tok0 + i) * 33 + d4];
                #pragma unroll
                for (int j = 0; j < 4; ++j) ev[j] = e32[(cg + j * 16) * 33 + d4];
                #pragma unroll
                for (int i = 0; i < 4; ++i)
                    #pragma unroll
                    for (int j = 0; j < 4; ++j) {
                        float a = acc[i][j];
                        a = __builtin_fmaf(rv[i].x, ev[j].x, a);
                        a = __builtin_fmaf(rv[i].y, ev[j].y, a);
                        a = __builtin_fmaf(rv[i].z, ev[j].z, a);
                        a = __builtin_fmaf(rv[i].w, ev[j].w, a);
                        acc[i][j] = a;
                    }
            }

            // ---- fold into running argmin (ascending c within thread) ----
            #pragma unroll
            for (int j = 0; j < 4; ++j) {
                const int   c  = c0 + cg + j * 16;
                const float ee = eet[cg + j * 16];
                #pragma unroll
                for (int i = 0; i < 4; ++i) {
                    float d = ee - 2.0f * acc[i][j];
                    if (d < m1[i]) { m1[i] = d; i1[i] = c; }
                }
            }
        }

        // ---- merge across the 16 cg-threads per token ----
        #pragma unroll
        for (int i = 0; i < 4; ++i) {
            mrg_m[tok0 + i][cg] = m1[i];
            mrg_i[tok0 + i][cg] = i1[i];
        }
        __syncthreads();
        if (tid < MT) {
            float gm = FLT_MAX;
            int   gi = 0x7fffffff;
            for (int g = 0; g < 16; ++g) {
                float em = mrg_m[tid][g];
                int   ei = mrg_i[tid][g];
                if (em < gm || (em == gm && ei < gi)) { gm = em; gi = ei; }
            }
            idxd[tid] = gi;
            code_out[(size_t)(gtok0 + tid) * KDEP + k] = gi;
        }
        __syncthreads();

        // ---- f32 residual update: r = fl(r - e[idx]) ----
        {
            const int tok = tid >> 2, q = tid & 3;
            const int idx = idxd[tok];
            const float4* ev = (const float4*)(ek + (size_t)idx * DDIM) + q * 8;
            #pragma unroll
            for (int t = 0; t < 8; ++t) {
                float4 f = ev[t];
                float4 rr = r32[tok * 33 + q * 8 + t];
                rr.x -= f.x; rr.y -= f.y; rr.z -= f.z; rr.w -= f.w;
                r32[tok * 33 + q * 8 + t] = rr;
            }
        }
        // next depth's tile-0 __syncthreads() guards these writes
    }
}

extern "C" void kernel_launch(void* const* d_in, const int* in_sizes, int n_in,
                              void* d_out, int out_size, void* d_ws, size_t ws_size,
                              hipStream_t stream) {
    (void)in_sizes; (void)n_in; (void)d_ws; (void)ws_size; (void)out_size;
    const float* embs = (const float*)d_in[0];
    const float* r    = (const float*)d_in[1];
    int* out = (int*)d_out;
    hipLaunchKernelGGL(rvq_encode_f32, dim3(NBLK), dim3(NTHREADS), 0, stream,
                       embs, r, out);
}

// Round 4
// 10486.749 us; speedup vs baseline: 1.0052x; 1.0052x over previous
//
#include <hip/hip_runtime.h>
#include <float.h>

#define KDEP 72
#define CSZ  1024
#define DDIM 128
#define MT   64          // tokens per block
#define TILE_CW 64       // codewords per LDS tile
#define NTILES 16
#define NTHREADS 256
#define NBLK 512         // 32768 / MT

// ---------------- kernel 1: precompute ||e||^2 (numpy pairwise-8 exact) ----
// One block per depth; 4 codewords per thread. Bit-identical to the
// previously-passing in-loop eet computation (rounded products via asm
// barrier, plain adds into 8 lanes, fixed combine tree).
__global__ void ee_precompute(const float* __restrict__ embs,
                              float* __restrict__ ee_out)
{
    const int k = blockIdx.x;
    const float* ek = embs + (size_t)k * (CSZ * DDIM);
    #pragma unroll
    for (int q = 0; q < 4; ++q) {
        const int cw = q * NTHREADS + threadIdx.x;
        const float4* ev = (const float4*)(ek + (size_t)cw * DDIM);
        float r8[8];
        #pragma unroll
        for (int j = 0; j < 8; ++j) r8[j] = 0.0f;
        for (int i = 0; i < 16; ++i) {          // dims 8i..8i+7
            float4 va = ev[2 * i];
            float4 vb = ev[2 * i + 1];
            float p0 = va.x * va.x; asm volatile("" : "+v"(p0));
            float p1 = va.y * va.y; asm volatile("" : "+v"(p1));
            float p2 = va.z * va.z; asm volatile("" : "+v"(p2));
            float p3 = va.w * va.w; asm volatile("" : "+v"(p3));
            float p4 = vb.x * vb.x; asm volatile("" : "+v"(p4));
            float p5 = vb.y * vb.y; asm volatile("" : "+v"(p5));
            float p6 = vb.z * vb.z; asm volatile("" : "+v"(p6));
            float p7 = vb.w * vb.w; asm volatile("" : "+v"(p7));
            r8[0] += p0; r8[1] += p1; r8[2] += p2; r8[3] += p3;
            r8[4] += p4; r8[5] += p5; r8[6] += p6; r8[7] += p7;
        }
        ee_out[(size_t)k * CSZ + cw] = ((r8[0] + r8[1]) + (r8[2] + r8[3]))
                                     + ((r8[4] + r8[5]) + (r8[6] + r8[7]));
    }
}

// ---------------- kernel 2: main RVQ encode (exact f32 chain) --------------
// dot(r,e) = sequential FMA over d ascending; dist = fmaf(-2, dot, ee)
// (== fl(ee - 2*dot)); update r = fl(r - e[idx]); argmin first-occurrence.
__launch_bounds__(NTHREADS, 2)
__global__ void rvq_encode_f32(const float* __restrict__ embs,
                               const float* __restrict__ r_in,
                               const float* __restrict__ ee_ws,
                               int* __restrict__ code_out)
{
    __shared__ float4 r32[MT * 33];          // [tok][33 float4] padded rows
    __shared__ float4 e32[TILE_CW * 32];     // [cw][32], slot c4 ^ (cw&7)
    __shared__ float  eeL[CSZ];              // per-depth ||e||^2
    __shared__ float  mrg_m[MT][17];
    __shared__ int    mrg_i[MT][17];
    __shared__ int    idxd[MT];

    const int tid  = threadIdx.x;
    const int tg   = tid >> 4;
    const int cg   = tid & 15;
    const int scg  = cg & 7;                 // (cg + j*16) & 7 == cg & 7
    const int tok0 = tg * 4;
    const long gtok0 = (long)blockIdx.x * MT;

    // ---- init f32 residual state in LDS ----
    {
        const int tok = tid >> 2, q = tid & 3;     // 4 threads/token, 32 floats each
        const float4* rsrc = (const float4*)(r_in + (size_t)(gtok0 + tok) * DDIM) + q * 8;
        #pragma unroll
        for (int t = 0; t < 8; ++t) r32[tok * 33 + q * 8 + t] = rsrc[t];
    }

    for (int k = 0; k < KDEP; ++k) {
        const float* ek = embs + (size_t)k * (CSZ * DDIM);

        // ---- preload this depth's ||e||^2 (1 float4/thread) ----
        ((float4*)eeL)[tid] = ((const float4*)(ee_ws + (size_t)k * CSZ))[tid];

        float m1[4];
        int   i1[4];
        #pragma unroll
        for (int i = 0; i < 4; ++i) { m1[i] = FLT_MAX; i1[i] = 0; }

        for (int tile = 0; tile < NTILES; ++tile) {
            const int c0 = tile * TILE_CW;
            // orders: prev-tile e32 readers done; eeL preload done (tile 0);
            // prev-depth r32 update writes done (tile 0)
            __syncthreads();

            // ---- stage codebook tile, coalesced reads, XOR-swizzled slots ----
            {
                const float4* gsrc = (const float4*)(ek + (size_t)c0 * DDIM);
                #pragma unroll
                for (int it = 0; it < 8; ++it) {
                    int u  = it * NTHREADS + tid;     // 0..2047 = cw*32 + c4
                    int cw = u >> 5, c4 = u & 31;
                    e32[cw * 32 + (c4 ^ (cw & 7))] = gsrc[u];
                }
            }
            __syncthreads();

            // ---- bulk f32 dots: 4 tokens x 4 codewords, sequential FMA ----
            float acc[4][4];
            #pragma unroll
            for (int i = 0; i < 4; ++i)
                #pragma unroll
                for (int j = 0; j < 4; ++j) acc[i][j] = 0.0f;

            #pragma unroll 4
            for (int d4 = 0; d4 < 32; ++d4) {         // ascending d
                float4 rv[4], ev[4];
                #pragma unroll
                for (int i = 0; i < 4; ++i) rv[i] = r32[(tok0 + i) * 33 + d4];
                #pragma unroll
                for (int j = 0; j < 4; ++j) ev[j] = e32[(cg + j * 16) * 32 + (d4 ^ scg)];
                #pragma unroll
                for (int i = 0; i < 4; ++i)
                    #pragma unroll
                    for (int j = 0; j < 4; ++j) {
                        float a = acc[i][j];
                        a = __builtin_fmaf(rv[i].x, ev[j].x, a);
                        a = __builtin_fmaf(rv[i].y, ev[j].y, a);
                        a = __builtin_fmaf(rv[i].z, ev[j].z, a);
                        a = __builtin_fmaf(rv[i].w, ev[j].w, a);
                        acc[i][j] = a;
                    }
            }

            // ---- fold into running argmin (ascending c within thread) ----
            #pragma unroll
            for (int j = 0; j < 4; ++j) {
                const int   c  = c0 + cg + j * 16;
                const float ee = eeL[c];
                #pragma unroll
                for (int i = 0; i < 4; ++i) {
                    // fl(ee - 2*acc): 2*acc exact, fma rounds once -> identical
                    float d = __builtin_fmaf(-2.0f, acc[i][j], ee);
                    if (d < m1[i]) { m1[i] = d; i1[i] = c; }
                }
            }
        }

        // ---- merge across the 16 cg-threads per token ----
        #pragma unroll
        for (int i = 0; i < 4; ++i) {
            mrg_m[tok0 + i][cg] = m1[i];
            mrg_i[tok0 + i][cg] = i1[i];
        }
        __syncthreads();
        if (tid < MT) {
            float gm = FLT_MAX;
            int   gi = 0x7fffffff;
            for (int g = 0; g < 16; ++g) {
                float em = mrg_m[tid][g];
                int   ei = mrg_i[tid][g];
                if (em < gm || (em == gm && ei < gi)) { gm = em; gi = ei; }
            }
            idxd[tid] = gi;
            code_out[(size_t)(gtok0 + tid) * KDEP + k] = gi;
        }
        __syncthreads();

        // ---- f32 residual update: r = fl(r - e[idx]) ----
        {
            const int tok = tid >> 2, q = tid & 3;
            const int idx = idxd[tok];
            const float4* ev = (const float4*)(ek + (size_t)idx * DDIM) + q * 8;
            #pragma unroll
            for (int t = 0; t < 8; ++t) {
                float4 f = ev[t];
                float4 rr = r32[tok * 33 + q * 8 + t];
                rr.x -= f.x; rr.y -= f.y; rr.z -= f.z; rr.w -= f.w;
                r32[tok * 33 + q * 8 + t] = rr;
            }
        }
        // next depth's tile-0 __syncthreads() guards these writes
    }
}

extern "C" void kernel_launch(void* const* d_in, const int* in_sizes, int n_in,
                              void* d_out, int out_size, void* d_ws, size_t ws_size,
                              hipStream_t stream) {
    (void)in_sizes; (void)n_in; (void)ws_size; (void)out_size;
    const float* embs = (const float*)d_in[0];
    const float* r    = (const float*)d_in[1];
    float* ee = (float*)d_ws;                 // 72*1024*4 B = 288 KiB scratch
    int* out = (int*)d_out;
    hipLaunchKernelGGL(ee_precompute, dim3(KDEP), dim3(NTHREADS), 0, stream,
                       embs, ee);
    hipLaunchKernelGGL(rvq_encode_f32, dim3(NBLK), dim3(NTHREADS), 0, stream,
                       embs, r, ee, out);
}

// Round 5
// 8369.610 us; speedup vs baseline: 1.2594x; 1.2530x over previous
//
#include <hip/hip_runtime.h>
#include <float.h>

#define KDEP 72
#define CSZ  1024
#define DDIM 128
#define MT   64          // tokens per block
#define TILE_CW 64       // codewords per LDS tile
#define NTILES 16
#define NTHREADS 256
#define NBLK 512         // 32768 / MT

typedef float f32x2 __attribute__((ext_vector_type(2)));
typedef float f32x4 __attribute__((ext_vector_type(4)));

// v_pk_fma_f32: D = S0*S1 + S2 per 32-bit half. Each half is a full IEEE f32
// FMA (bit-identical to v_fma_f32). op_sel arrays are [S0,S1,S2];
// op_sel    selects the source half feeding the LOW  result half,
// op_sel_hi selects the source half feeding the HIGH result half.
// acc/rp packed normally; ep broadcast from its .x (LO) or .y (HI).
#define PK_FMA_LO(acc, rp, ep) \
    asm("v_pk_fma_f32 %0, %1, %2, %0 op_sel:[0,0,0] op_sel_hi:[1,0,1]" \
        : "+v"(acc) : "v"(rp), "v"(ep))
#define PK_FMA_HI(acc, rp, ep) \
    asm("v_pk_fma_f32 %0, %1, %2, %0 op_sel:[0,1,0] op_sel_hi:[1,1,1]" \
        : "+v"(acc) : "v"(rp), "v"(ep))

// ---------------- kernel 1: precompute ||e||^2 (numpy pairwise-8 exact) ----
__global__ void ee_precompute(const float* __restrict__ embs,
                              float* __restrict__ ee_out)
{
    const int k = blockIdx.x;
    const float* ek = embs + (size_t)k * (CSZ * DDIM);
    #pragma unroll
    for (int q = 0; q < 4; ++q) {
        const int cw = q * NTHREADS + threadIdx.x;
        const float4* ev = (const float4*)(ek + (size_t)cw * DDIM);
        float r8[8];
        #pragma unroll
        for (int j = 0; j < 8; ++j) r8[j] = 0.0f;
        for (int i = 0; i < 16; ++i) {          // dims 8i..8i+7
            float4 va = ev[2 * i];
            float4 vb = ev[2 * i + 1];
            float p0 = va.x * va.x; asm volatile("" : "+v"(p0));
            float p1 = va.y * va.y; asm volatile("" : "+v"(p1));
            float p2 = va.z * va.z; asm volatile("" : "+v"(p2));
            float p3 = va.w * va.w; asm volatile("" : "+v"(p3));
            float p4 = vb.x * vb.x; asm volatile("" : "+v"(p4));
            float p5 = vb.y * vb.y; asm volatile("" : "+v"(p5));
            float p6 = vb.z * vb.z; asm volatile("" : "+v"(p6));
            float p7 = vb.w * vb.w; asm volatile("" : "+v"(p7));
            r8[0] += p0; r8[1] += p1; r8[2] += p2; r8[3] += p3;
            r8[4] += p4; r8[5] += p5; r8[6] += p6; r8[7] += p7;
        }
        ee_out[(size_t)k * CSZ + cw] = ((r8[0] + r8[1]) + (r8[2] + r8[3]))
                                     + ((r8[4] + r8[5]) + (r8[6] + r8[7]));
    }
}

// ---------------- kernel 2: main RVQ encode (exact f32 chain, pk-FMA) ------
// dot(r,e) = sequential FMA over d ascending (each pk half = 1 dim/step);
// dist = fmaf(-2, dot, ee); update r = fl(r - e[idx]); argmin first-occurrence.
__launch_bounds__(NTHREADS, 2)
__global__ void rvq_encode_f32(const float* __restrict__ embs,
                               const float* __restrict__ r_in,
                               const float* __restrict__ ee_ws,
                               int* __restrict__ code_out)
{
    __shared__ __align__(16) float rt[DDIM][MT];   // transposed residuals [d][tok]
    __shared__ float4 e32[TILE_CW * 33];           // [cw][33 float4] pad-33 rows
    __shared__ float  eeL[CSZ];
    __shared__ float  mrg_m[MT][16];
    __shared__ int    mrg_i[MT][16];
    __shared__ int    idxd[MT];

    const int tid  = threadIdx.x;
    const int tg   = tid >> 4;
    const int cg   = tid & 15;
    const int tok0 = tg * 4;
    const long gtok0 = (long)blockIdx.x * MT;

    // ---- init residual state: global [tok][d] -> LDS rt[d][tok] ----
    {
        const int tok = tid >> 2, q = tid & 3;     // 4 threads/token, 32 dims each
        const float4* rsrc = (const float4*)(r_in + (size_t)(gtok0 + tok) * DDIM) + q * 8;
        #pragma unroll
        for (int t = 0; t < 8; ++t) {
            float4 f = rsrc[t];
            const int d = q * 32 + t * 4;
            rt[d + 0][tok] = f.x; rt[d + 1][tok] = f.y;
            rt[d + 2][tok] = f.z; rt[d + 3][tok] = f.w;
        }
    }

    for (int k = 0; k < KDEP; ++k) {
        const float* ek = embs + (size_t)k * (CSZ * DDIM);

        // ---- preload this depth's ||e||^2 ----
        ((float4*)eeL)[tid] = ((const float4*)(ee_ws + (size_t)k * CSZ))[tid];

        float m1[4];
        int   i1[4];
        #pragma unroll
        for (int i = 0; i < 4; ++i) { m1[i] = FLT_MAX; i1[i] = 0; }

        for (int tile = 0; tile < NTILES; ++tile) {
            const int c0 = tile * TILE_CW;
            // orders: prev-tile e32 readers done; eeL preload done (tile 0);
            // prev-depth rt update writes done (tile 0)
            __syncthreads();

            // ---- stage codebook tile (coalesced, pad-33 rows) ----
            {
                const float4* gsrc = (const float4*)(ek + (size_t)c0 * DDIM);
                #pragma unroll
                for (int it = 0; it < 8; ++it) {
                    int u  = it * NTHREADS + tid;     // 0..2047 = cw*32 + c4
                    int cw = u >> 5, c4 = u & 31;
                    e32[cw * 33 + c4] = gsrc[u];
                }
            }
            __syncthreads();

            // ---- bulk distances: 4 tokens x 4 codewords, pk-FMA over d ----
            // acc[ip][j]: ip=token-pair (tok0+2ip, tok0+2ip+1), j=cw cg+j*16
            f32x2 acc[2][4];
            #pragma unroll
            for (int ip = 0; ip < 2; ++ip)
                #pragma unroll
                for (int j = 0; j < 4; ++j) acc[ip][j] = (f32x2)(0.0f);

            #pragma unroll 2
            for (int dg = 0; dg < 32; ++dg) {         // 4 dims per step, ascending
                f32x4 rv[4];
                f32x4 ev[4];
                #pragma unroll
                for (int dd = 0; dd < 4; ++dd)
                    rv[dd] = *(const f32x4*)&rt[dg * 4 + dd][tok0];
                #pragma unroll
                for (int j = 0; j < 4; ++j)
                    ev[j] = *(const f32x4*)&e32[(cg + j * 16) * 33 + dg];

                #pragma unroll
                for (int dd = 0; dd < 4; ++dd) {
                    f32x2 rp0 = __builtin_shufflevector(rv[dd], rv[dd], 0, 1);
                    f32x2 rp1 = __builtin_shufflevector(rv[dd], rv[dd], 2, 3);
                    #pragma unroll
                    for (int j = 0; j < 4; ++j) {
                        f32x2 ep = (dd < 2)
                            ? __builtin_shufflevector(ev[j], ev[j], 0, 1)
                            : __builtin_shufflevector(ev[j], ev[j], 2, 3);
                        if (dd & 1) {
                            PK_FMA_HI(acc[0][j], rp0, ep);
                            PK_FMA_HI(acc[1][j], rp1, ep);
                        } else {
                            PK_FMA_LO(acc[0][j], rp0, ep);
                            PK_FMA_LO(acc[1][j], rp1, ep);
                        }
                    }
                }
            }

            // ---- fold into running argmin (c ascending within thread) ----
            #pragma unroll
            for (int j = 0; j < 4; ++j) {
                const int   c  = c0 + cg + j * 16;
                const float ee = eeL[c];
                float d0 = __builtin_fmaf(-2.0f, acc[0][j].x, ee);  // tok0+0
                float d1 = __builtin_fmaf(-2.0f, acc[0][j].y, ee);  // tok0+1
                float d2 = __builtin_fmaf(-2.0f, acc[1][j].x, ee);  // tok0+2
                float d3 = __builtin_fmaf(-2.0f, acc[1][j].y, ee);  // tok0+3
                if (d0 < m1[0]) { m1[0] = d0; i1[0] = c; }
                if (d1 < m1[1]) { m1[1] = d1; i1[1] = c; }
                if (d2 < m1[2]) { m1[2] = d2; i1[2] = c; }
                if (d3 < m1[3]) { m1[3] = d3; i1[3] = c; }
            }
        }

        // ---- merge across the 16 cg-threads per token ----
        #pragma unroll
        for (int i = 0; i < 4; ++i) {
            mrg_m[tok0 + i][cg] = m1[i];
            mrg_i[tok0 + i][cg] = i1[i];
        }
        __syncthreads();
        if (tid < MT) {
            float gm = FLT_MAX;
            int   gi = 0x7fffffff;
            for (int g = 0; g < 16; ++g) {
                float em = mrg_m[tid][g];
                int   ei = mrg_i[tid][g];
                if (em < gm || (em == gm && ei < gi)) { gm = em; gi = ei; }
            }
            idxd[tid] = gi;
            code_out[(size_t)(gtok0 + tid) * KDEP + k] = gi;
        }
        __syncthreads();

        // ---- f32 residual update: rt[d][tok] = fl(rt - e[idx][d]) ----
        {
            const int tok = tid >> 2, q = tid & 3;
            const int idx = idxd[tok];
            const float4* ev = (const float4*)(ek + (size_t)idx * DDIM) + q * 8;
            #pragma unroll
            for (int t = 0; t < 8; ++t) {
                float4 f = ev[t];
                const int d = q * 32 + t * 4;
                rt[d + 0][tok] -= f.x;
                rt[d + 1][tok] -= f.y;
                rt[d + 2][tok] -= f.z;
                rt[d + 3][tok] -= f.w;
            }
        }
        // next depth's tile-0 __syncthreads() guards these writes
    }
}

extern "C" void kernel_launch(void* const* d_in, const int* in_sizes, int n_in,
                              void* d_out, int out_size, void* d_ws, size_t ws_size,
                              hipStream_t stream) {
    (void)in_sizes; (void)n_in; (void)ws_size; (void)out_size;
    const float* embs = (const float*)d_in[0];
    const float* r    = (const float*)d_in[1];
    float* ee = (float*)d_ws;                 // 72*1024*4 B = 288 KiB scratch
    int* out = (int*)d_out;
    hipLaunchKernelGGL(ee_precompute, dim3(KDEP), dim3(NTHREADS), 0, stream,
                       embs, ee);
    hipLaunchKernelGGL(rvq_encode_f32, dim3(NBLK), dim3(NTHREADS), 0, stream,
                       embs, r, ee, out);
}

// Round 6
// 7648.209 us; speedup vs baseline: 1.3782x; 1.0943x over previous
//
#include <hip/hip_runtime.h>
#include <float.h>

#define KDEP 72
#define CSZ  1024
#define DDIM 128
#define MT   128         // tokens per block
#define TILE_CW 128      // codewords per LDS tile
#define NTILES 8
#define NTHREADS 256
#define NBLK 256         // 32768 / MT

typedef float f32x2 __attribute__((ext_vector_type(2)));
typedef float f32x4 __attribute__((ext_vector_type(4)));

// v_pk_fma_f32: D = S0*S1 + S2 per 32-bit half; each half is a full IEEE f32
// FMA. op_sel/op_sel_hi choose source halves for the LO/HI result halves.
// S0 (r pair) and S2 (acc) flow packed; S1 (e) is splat from .x (LO) / .y (HI).
#define PK_FMA_LO(acc, rp, ep) \
    asm("v_pk_fma_f32 %0, %1, %2, %0 op_sel:[0,0,0] op_sel_hi:[1,0,1]" \
        : "+v"(acc) : "v"(rp), "v"(ep))
#define PK_FMA_HI(acc, rp, ep) \
    asm("v_pk_fma_f32 %0, %1, %2, %0 op_sel:[0,1,0] op_sel_hi:[1,1,1]" \
        : "+v"(acc) : "v"(rp), "v"(ep))

// ---------------- kernel 1: precompute ||e||^2 (numpy pairwise-8 exact) ----
__global__ void ee_precompute(const float* __restrict__ embs,
                              float* __restrict__ ee_out)
{
    const int k = blockIdx.x;
    const float* ek = embs + (size_t)k * (CSZ * DDIM);
    #pragma unroll
    for (int q = 0; q < 4; ++q) {
        const int cw = q * NTHREADS + threadIdx.x;
        const float4* ev = (const float4*)(ek + (size_t)cw * DDIM);
        float r8[8];
        #pragma unroll
        for (int j = 0; j < 8; ++j) r8[j] = 0.0f;
        for (int i = 0; i < 16; ++i) {          // dims 8i..8i+7
            float4 va = ev[2 * i];
            float4 vb = ev[2 * i + 1];
            float p0 = va.x * va.x; asm volatile("" : "+v"(p0));
            float p1 = va.y * va.y; asm volatile("" : "+v"(p1));
            float p2 = va.z * va.z; asm volatile("" : "+v"(p2));
            float p3 = va.w * va.w; asm volatile("" : "+v"(p3));
            float p4 = vb.x * vb.x; asm volatile("" : "+v"(p4));
            float p5 = vb.y * vb.y; asm volatile("" : "+v"(p5));
            float p6 = vb.z * vb.z; asm volatile("" : "+v"(p6));
            float p7 = vb.w * vb.w; asm volatile("" : "+v"(p7));
            r8[0] += p0; r8[1] += p1; r8[2] += p2; r8[3] += p3;
            r8[4] += p4; r8[5] += p5; r8[6] += p6; r8[7] += p7;
        }
        ee_out[(size_t)k * CSZ + cw] = ((r8[0] + r8[1]) + (r8[2] + r8[3]))
                                     + ((r8[4] + r8[5]) + (r8[6] + r8[7]));
    }
}

// ---------------- kernel 2: main RVQ encode (exact f32 chain, 8x8 tile) ----
// Per thread: 8 tokens x 8 codewords. dot = sequential pk-FMA over d ascending
// (one dim per pk half per step); dist = fmaf(-2,dot,ee); update = fl(r - e).
__launch_bounds__(NTHREADS, 1)
__global__ void rvq_encode_f32(const float* __restrict__ embs,
                               const float* __restrict__ r_in,
                               const float* __restrict__ ee_ws,
                               int* __restrict__ code_out)
{
    __shared__ __align__(16) float rt[DDIM][MT];   // transposed residuals [d][tok] 64 KB
    __shared__ float4 et[TILE_CW * 33];            // [cw][33 float4] pad rows, 66 KB
    __shared__ float  eeL[CSZ];
    __shared__ float  mrg_m[MT][16];
    __shared__ int    mrg_i[MT][16];
    __shared__ int    idxd[MT];

    const int tid  = threadIdx.x;
    const int tg   = tid >> 4;
    const int cg   = tid & 15;
    const int tok0 = tg * 8;
    const long gtok0 = (long)blockIdx.x * MT;

    // ---- init residual state: global [tok][d] -> LDS rt[d][tok] ----
    {
        const int tok = tid >> 1, half = tid & 1;  // 2 threads/token, 64 dims each
        const float4* rsrc = (const float4*)(r_in + (size_t)(gtok0 + tok) * DDIM) + half * 16;
        #pragma unroll
        for (int t = 0; t < 16; ++t) {
            float4 f = rsrc[t];
            const int d = half * 64 + t * 4;
            rt[d + 0][tok] = f.x; rt[d + 1][tok] = f.y;
            rt[d + 2][tok] = f.z; rt[d + 3][tok] = f.w;
        }
    }

    for (int k = 0; k < KDEP; ++k) {
        const float* ek = embs + (size_t)k * (CSZ * DDIM);

        // ---- preload this depth's ||e||^2 ----
        ((float4*)eeL)[tid] = ((const float4*)(ee_ws + (size_t)k * CSZ))[tid];

        float m1[8];
        int   i1[8];
        #pragma unroll
        for (int i = 0; i < 8; ++i) { m1[i] = FLT_MAX; i1[i] = 0; }

        for (int tile = 0; tile < NTILES; ++tile) {
            const int c0 = tile * TILE_CW;
            // guards: prev-tile et readers done; eeL preload done (tile 0);
            // prev-depth rt update writes done (tile 0)
            __syncthreads();

            // ---- stage codebook tile (coalesced, pad-33 rows) ----
            {
                const float4* gsrc = (const float4*)(ek + (size_t)c0 * DDIM);
                #pragma unroll
                for (int it = 0; it < 16; ++it) {
                    int u  = it * NTHREADS + tid;     // 0..4095 = cw*32 + c4
                    int cw = u >> 5, c4 = u & 31;
                    et[cw * 33 + c4] = gsrc[u];
                }
            }
            __syncthreads();

            // ---- bulk distances: 8 tokens x 8 codewords, pk-FMA over d ----
            // acc[p][j]: p = token pair (tok0+2p, tok0+2p+1), j = cw cg+j*16
            f32x2 acc[4][8];
            #pragma unroll
            for (int p = 0; p < 4; ++p)
                #pragma unroll
                for (int j = 0; j < 8; ++j) acc[p][j] = (f32x2)(0.0f);

            #pragma unroll 2
            for (int dg = 0; dg < 32; ++dg) {         // 4 dims per step, ascending
                f32x4 ev[8];
                #pragma unroll
                for (int j = 0; j < 8; ++j)
                    ev[j] = *(const f32x4*)&et[(cg + j * 16) * 33 + dg];

                #pragma unroll
                for (int dd = 0; dd < 4; ++dd) {
                    const int d = dg * 4 + dd;
                    f32x4 rva = *(const f32x4*)&rt[d][tok0];
                    f32x4 rvb = *(const f32x4*)&rt[d][tok0 + 4];
                    f32x2 rp0 = __builtin_shufflevector(rva, rva, 0, 1);
                    f32x2 rp1 = __builtin_shufflevector(rva, rva, 2, 3);
                    f32x2 rp2 = __builtin_shufflevector(rvb, rvb, 0, 1);
                    f32x2 rp3 = __builtin_shufflevector(rvb, rvb, 2, 3);
                    #pragma unroll
                    for (int j = 0; j < 8; ++j) {
                        f32x2 ep = (dd < 2)
                            ? __builtin_shufflevector(ev[j], ev[j], 0, 1)
                            : __builtin_shufflevector(ev[j], ev[j], 2, 3);
                        if (dd & 1) {
                            PK_FMA_HI(acc[0][j], rp0, ep);
                            PK_FMA_HI(acc[1][j], rp1, ep);
                            PK_FMA_HI(acc[2][j], rp2, ep);
                            PK_FMA_HI(acc[3][j], rp3, ep);
                        } else {
                            PK_FMA_LO(acc[0][j], rp0, ep);
                            PK_FMA_LO(acc[1][j], rp1, ep);
                            PK_FMA_LO(acc[2][j], rp2, ep);
                            PK_FMA_LO(acc[3][j], rp3, ep);
                        }
                    }
                }
            }

            // ---- fold into running argmin (c ascending within thread) ----
            #pragma unroll
            for (int j = 0; j < 8; ++j) {
                const int   c  = c0 + cg + j * 16;
                const float ee = eeL[c];
                #pragma unroll
                for (int p = 0; p < 4; ++p) {
                    float dlo = __builtin_fmaf(-2.0f, acc[p][j].x, ee);  // tok0+2p
                    float dhi = __builtin_fmaf(-2.0f, acc[p][j].y, ee);  // tok0+2p+1
                    if (dlo < m1[2 * p])     { m1[2 * p] = dlo;     i1[2 * p] = c; }
                    if (dhi < m1[2 * p + 1]) { m1[2 * p + 1] = dhi; i1[2 * p + 1] = c; }
                }
            }
        }

        // ---- merge across the 16 cg-threads per token ----
        #pragma unroll
        for (int i = 0; i < 8; ++i) {
            mrg_m[tok0 + i][cg] = m1[i];
            mrg_i[tok0 + i][cg] = i1[i];
        }
        __syncthreads();
        if (tid < MT) {
            float gm = FLT_MAX;
            int   gi = 0x7fffffff;
            for (int g = 0; g < 16; ++g) {
                float em = mrg_m[tid][g];
                int   ei = mrg_i[tid][g];
                if (em < gm || (em == gm && ei < gi)) { gm = em; gi = ei; }
            }
            idxd[tid] = gi;
            code_out[(size_t)(gtok0 + tid) * KDEP + k] = gi;
        }
        __syncthreads();

        // ---- f32 residual update: rt[d][tok] = fl(rt - e[idx][d]) ----
        {
            const int tok = tid >> 1, half = tid & 1;
            const int idx = idxd[tok];
            const float4* ev4 = (const float4*)(ek + (size_t)idx * DDIM) + half * 16;
            #pragma unroll
            for (int t = 0; t < 16; ++t) {
                float4 f = ev4[t];
                const int d = half * 64 + t * 4;
                rt[d + 0][tok] -= f.x;
                rt[d + 1][tok] -= f.y;
                rt[d + 2][tok] -= f.z;
                rt[d + 3][tok] -= f.w;
            }
        }
        // next depth's tile-0 __syncthreads() guards these writes
    }
}

extern "C" void kernel_launch(void* const* d_in, const int* in_sizes, int n_in,
                              void* d_out, int out_size, void* d_ws, size_t ws_size,
                              hipStream_t stream) {
    (void)in_sizes; (void)n_in; (void)ws_size; (void)out_size;
    const float* embs = (const float*)d_in[0];
    const float* r    = (const float*)d_in[1];
    float* ee = (float*)d_ws;                 // 72*1024*4 B = 288 KiB scratch
    int* out = (int*)d_out;
    hipLaunchKernelGGL(ee_precompute, dim3(KDEP), dim3(NTHREADS), 0, stream,
                       embs, ee);
    hipLaunchKernelGGL(rvq_encode_f32, dim3(NBLK), dim3(NTHREADS), 0, stream,
                       embs, r, ee, out);
}